// Round 4
// baseline (60.633 us; speedup 1.0000x reference)
//
#include <hip/hip_runtime.h>
#include <hip/hip_bf16.h>

// ws layout: bf16 NHWC copies of the 4 feature levels (element offsets)
static constexpr size_t B3 = 0;
static constexpr size_t B4 = (size_t)4 * 256 * 16384;                 // after f3
static constexpr size_t B5 = B4 + (size_t)4 * 256 * 4096;             // after f4
static constexpr size_t B6 = B5 + (size_t)4 * 256 * 1024;             // after f5
static constexpr size_t WS_ELEMS = B6 + (size_t)4 * 256 * 256;        // bf16 elems

// ---------------- NCHW fp32 -> NHWC bf16 transpose -------------------------
__global__ __launch_bounds__(256) void transpose_nchw_nhwc_bf16(
    const float* __restrict__ f3, const float* __restrict__ f4,
    const float* __restrict__ f5, const float* __restrict__ f6,
    __hip_bfloat16* __restrict__ ws)
{
    __shared__ float tile[64][65];
    const int z   = blockIdx.z;         // lvl*4 + b
    const int lvl = z >> 2;
    const int b   = z & 3;
    const float* in; int H; size_t base;
    if      (lvl == 0) { in = f3; H = 128; base = B3; }
    else if (lvl == 1) { in = f4; H = 64;  base = B4; }
    else if (lvl == 2) { in = f5; H = 32;  base = B5; }
    else               { in = f6; H = 16;  base = B6; }
    const int HW  = H * H;
    const int hw0 = blockIdx.x * 64;
    if (hw0 >= HW) return;
    const int c0  = blockIdx.y * 64;
    const int tx  = threadIdx.x & 63;
    const int ty  = threadIdx.x >> 6;

    const float* inp = in + ((size_t)b * 256 + c0) * (size_t)HW + hw0;
    #pragma unroll
    for (int i = 0; i < 16; ++i) {
        const int cl = ty + 4 * i;
        tile[cl][tx] = inp[(size_t)cl * HW + tx];          // 256B/wave coalesced
    }
    __syncthreads();
    __hip_bfloat16* outp = ws + base + ((size_t)b * HW + hw0) * 256 + c0;
    #pragma unroll
    for (int i = 0; i < 16; ++i) {
        const int hl = ty + 4 * i;
        outp[(size_t)hl * 256 + tx] = __float2bfloat16(tile[tx][hl]);  // 128B/wave
    }
}

// ---------------- ROI gather from bf16 NHWC --------------------------------
// one block per ROI, 512 threads (8 waves); lane = 4 channels (uint2)
__device__ __forceinline__ float bf_lo(unsigned u) { return __uint_as_float(u << 16); }
__device__ __forceinline__ float bf_hi(unsigned u) { return __uint_as_float(u & 0xffff0000u); }

__global__ __launch_bounds__(512) void roi_gather_nhwc_bf16(
    const uint2* __restrict__ ws, const float* __restrict__ boxes,
    const int* __restrict__ img_ids, float* __restrict__ out)
{
    __shared__ float lds[49][261];      // [bin][perm(ch)] staging (261 coprime 32)
    __shared__ float rW[14][2];         // {hy, ly}  (zeroed if row-invalid)
    __shared__ int   rO[14][2];         // {yl, yh} * H * 64  (uint2 offsets)
    __shared__ float cW[14][2];         // {hx, lx}  (zeroed if col-invalid)
    __shared__ int   cO[14][2];         // {xl, xh} * 64

    const int n    = blockIdx.x;        // ROI
    const int t    = threadIdx.x;
    const int lane = t & 63;
    const int wv   = t >> 6;            // 0..7

    const float by = boxes[n * 4 + 0];
    const float bx = boxes[n * 4 + 1];
    const float bh = boxes[n * 4 + 2];
    const float bw = boxes[n * 4 + 3];

    float kf = floorf(4.0f + log2f(sqrtf(bh * bw) / 224.0f));
    kf = fminf(fmaxf(kf, 3.0f), 6.0f);
    const int lvl = (int)kf;

    int H; size_t base;
    if      (lvl == 3) { H = 128; base = B3; }
    else if (lvl == 4) { H = 64;  base = B4; }
    else if (lvl == 5) { H = 32;  base = B5; }
    else               { H = 16;  base = B6; }
    const float inv_stride = 1.0f / (float)(1 << lvl);
    const float Hf = (float)H;

    // tlbr/stride with the reference's swapped axis semantics (rounds 1-3 verified)
    const float tY = (by - bh * 0.5f) * inv_stride;
    const float lX = (bx - bw * 0.5f) * inv_stride;
    const float bY = (by + bh * 0.5f) * inv_stride;
    const float rX = (bx + bw * 0.5f) * inv_stride;
    const float binA = fmaxf(bY - tY, 1.0f) * (1.0f / 7.0f);  // col direction
    const float binB = fmaxf(rX - lX, 1.0f) * (1.0f / 7.0f);  // row direction

    // separable sampling tables: 14 row coords (wave 0), 14 col coords (wave 1)
    if (lane < 14 && wv < 2) {
        const int a = lane;
        const float off = (float)(a >> 1) + 0.25f + 0.5f * (float)(a & 1);
        if (wv == 0) {
            const float rc = lX + off * binB;
            const bool v = (rc >= -1.0f) && (rc <= Hf);
            const float yc = fminf(fmaxf(rc, 0.0f), Hf - 1.0f);
            const int yl = (int)yc;
            const int yh = min(yl + 1, H - 1);
            const float ly = yc - (float)yl;
            rW[a][0] = v ? 1.0f - ly : 0.0f;
            rW[a][1] = v ? ly : 0.0f;
            rO[a][0] = yl * H * 64;
            rO[a][1] = yh * H * 64;
        } else {
            const float cc = tY + off * binA;
            const bool v = (cc >= -1.0f) && (cc <= Hf);
            const float xc = fminf(fmaxf(cc, 0.0f), Hf - 1.0f);
            const int xl = (int)xc;
            const int xh = min(xl + 1, H - 1);
            const float lx = xc - (float)xl;
            cW[a][0] = v ? 1.0f - lx : 0.0f;
            cW[a][1] = v ? lx : 0.0f;
            cO[a][0] = xl * 64;
            cO[a][1] = xh * 64;
        }
    }
    __syncthreads();

    const int img = img_ids[n];
    // uint2 units: 4 bf16 channels each; lane covers channels 4*lane..4*lane+3
    const uint2* fb = ws + (base >> 2) + (size_t)img * (size_t)(H * H) * 64 + lane;

    for (int p = wv; p < 49; p += 8) {
        const int a0 = (p / 7) * 2;
        const int b0 = (p % 7) * 2;
        float a0c = 0.0f, a1c = 0.0f, a2c = 0.0f, a3c = 0.0f;
        #pragma unroll
        for (int s1 = 0; s1 < 2; ++s1) {
            const float hy = rW[a0 + s1][0], lyw = rW[a0 + s1][1];
            const int oy0 = rO[a0 + s1][0], oy1 = rO[a0 + s1][1];
            #pragma unroll
            for (int s2 = 0; s2 < 2; ++s2) {
                const float hx = cW[b0 + s2][0], lxw = cW[b0 + s2][1];
                const int ox0 = cO[b0 + s2][0], ox1 = cO[b0 + s2][1];
                const uint2 u00 = fb[oy0 + ox0];
                const uint2 u01 = fb[oy0 + ox1];
                const uint2 u10 = fb[oy1 + ox0];
                const uint2 u11 = fb[oy1 + ox1];
                const float w00 = hy * hx, w01 = hy * lxw;
                const float w10 = lyw * hx, w11 = lyw * lxw;
                a0c += w00 * bf_lo(u00.x) + w01 * bf_lo(u01.x)
                     + w10 * bf_lo(u10.x) + w11 * bf_lo(u11.x);
                a1c += w00 * bf_hi(u00.x) + w01 * bf_hi(u01.x)
                     + w10 * bf_hi(u10.x) + w11 * bf_hi(u11.x);
                a2c += w00 * bf_lo(u00.y) + w01 * bf_lo(u01.y)
                     + w10 * bf_lo(u10.y) + w11 * bf_lo(u11.y);
                a3c += w00 * bf_hi(u00.y) + w01 * bf_hi(u01.y)
                     + w10 * bf_hi(u10.y) + w11 * bf_hi(u11.y);
            }
        }
        // channel c stored at col perm(c) = (c>>2) + 64*(c&3): lane-stride-1 writes
        lds[p][lane]       = a0c * 0.25f;
        lds[p][lane + 64]  = a1c * 0.25f;
        lds[p][lane + 128] = a2c * 0.25f;
        lds[p][lane + 192] = a3c * 0.25f;
    }
    __syncthreads();

    // coalesced NCHW write-out: lanes = bins (49 active), wave w -> channels 32w..
    float* op = out + (size_t)n * 256 * 49;
    if (lane < 49) {
        #pragma unroll 4
        for (int k = 0; k < 32; ++k) {
            const int c = wv * 32 + k;
            const int pc = (c >> 2) + 64 * (c & 3);
            op[(size_t)c * 49 + lane] = lds[lane][pc];
        }
    }
}

// ---------------- fallback (round-1, direct NCHW gather) -------------------
__global__ __launch_bounds__(256) void roi_align_fallback(
    const float* __restrict__ f3, const float* __restrict__ f4,
    const float* __restrict__ f5, const float* __restrict__ f6,
    const float* __restrict__ boxes, const int* __restrict__ img_ids,
    float* __restrict__ out)
{
    const int n  = blockIdx.x;
    const int cg = blockIdx.y;
    const int t  = threadIdx.x;

    const float by = boxes[n * 4 + 0];
    const float bx = boxes[n * 4 + 1];
    const float bh = boxes[n * 4 + 2];
    const float bw = boxes[n * 4 + 3];

    float kf = floorf(4.0f + log2f(sqrtf(bh * bw) / 224.0f));
    kf = fminf(fmaxf(kf, 3.0f), 6.0f);
    const int lvl = (int)kf;

    const float* feat;
    int H;
    if      (lvl == 3) { feat = f3; H = 128; }
    else if (lvl == 4) { feat = f4; H = 64;  }
    else if (lvl == 5) { feat = f5; H = 32;  }
    else               { feat = f6; H = 16;  }

    const float inv_stride = 1.0f / (float)(1 << lvl);
    const float tY = (by - bh * 0.5f) * inv_stride;
    const float lX = (bx - bw * 0.5f) * inv_stride;
    const float bY = (by + bh * 0.5f) * inv_stride;
    const float rX = (bx + bw * 0.5f) * inv_stride;
    const float binA = fmaxf(bY - tY, 1.0f) / 7.0f;
    const float binB = fmaxf(rX - lX, 1.0f) / 7.0f;

    const int p   = t >> 2;
    const int s1  = (t >> 1) & 1;
    const int s2  = t & 1;
    const int ii  = p / 7;
    const int jj  = p % 7;
    const bool active = (t < 196);

    const float rc = lX + ((float)ii + ((float)s1 + 0.5f) * 0.5f) * binB;
    const float cc = tY + ((float)jj + ((float)s2 + 0.5f) * 0.5f) * binA;
    const float Hf = (float)H;
    const bool valid = active && (rc >= -1.0f) && (rc <= Hf) &&
                       (cc >= -1.0f) && (cc <= Hf);

    const float yc = fminf(fmaxf(rc, 0.0f), Hf - 1.0f);
    const float xc = fminf(fmaxf(cc, 0.0f), Hf - 1.0f);
    int yl = (int)floorf(yc);
    int xl = (int)floorf(xc);
    int yh = min(yl + 1, H - 1);
    int xh = min(xl + 1, H - 1);
    const float ly = yc - (float)yl;
    const float lx = xc - (float)xl;
    const float hy = 1.0f - ly;
    const float hx = 1.0f - lx;
    float w00 = hy * hx, w01 = hy * lx, w10 = ly * hx, w11 = ly * lx;
    if (!valid) { w00 = w01 = w10 = w11 = 0.0f; yl = xl = yh = xh = 0; }

    const int img = img_ids[n];
    const int HH  = H * H;
    const int c0  = cg * 64;
    const float* basep = feat + (size_t)(img * 256 + c0) * (size_t)HH;
    const int o00 = yl * H + xl, o01 = yl * H + xh;
    const int o10 = yh * H + xl, o11 = yh * H + xh;

    float* outp = out + ((size_t)n * 256 + c0) * 49 + p;
    #pragma unroll 4
    for (int c = 0; c < 64; ++c) {
        float v = w00 * basep[o00] + w01 * basep[o01]
                + w10 * basep[o10] + w11 * basep[o11];
        v += __shfl_xor(v, 1);
        v += __shfl_xor(v, 2);
        if (active && (t & 3) == 0) outp[(size_t)c * 49] = v * 0.25f;
        basep += HH;
    }
}

extern "C" void kernel_launch(void* const* d_in, const int* in_sizes, int n_in,
                              void* d_out, int out_size, void* d_ws, size_t ws_size,
                              hipStream_t stream)
{
    const float* f3      = (const float*)d_in[0];
    const float* f4      = (const float*)d_in[1];
    const float* f5      = (const float*)d_in[2];
    const float* f6      = (const float*)d_in[3];
    const float* boxes   = (const float*)d_in[4];
    const int*   img_ids = (const int*)d_in[5];
    float* outp          = (float*)d_out;
    const int N = in_sizes[5];                    // 1024 ROIs

    if (ws_size >= WS_ELEMS * sizeof(__hip_bfloat16)) {
        dim3 tgrid(256, 4, 16);                   // (hw tiles max, c tiles, lvl*4+b)
        transpose_nchw_nhwc_bf16<<<tgrid, 256, 0, stream>>>(
            f3, f4, f5, f6, (__hip_bfloat16*)d_ws);
        roi_gather_nhwc_bf16<<<N, 512, 0, stream>>>(
            (const uint2*)d_ws, boxes, img_ids, outp);
    } else {
        dim3 grid(N, 4);
        roi_align_fallback<<<grid, 256, 0, stream>>>(f3, f4, f5, f6, boxes, img_ids, outp);
    }
}